// Round 2
// baseline (1881.042 us; speedup 1.0000x reference)
//
#include <hip/hip_runtime.h>
#include <hip/hip_bf16.h>

// GCN 2-layer, fp32 I/O:
//   h   = relu(segsum_dst((x@W1)[src1] * w1))      128 -> 64
//   out = segsum_dst((h@W2)[src2] * w2)            64 -> 16
// N=100000 nodes, E=1600000 edges.
// ws (fp32): h1[N*64] | agg1[N*64] | h2[N*16]  = 57.6 MB

__global__ void gemm1_kernel(const float* __restrict__ x,
                             const float* __restrict__ W1,
                             float* __restrict__ h1, int n_nodes) {
    // 8 nodes per block; 4 waves, each wave computes 64 out-feats for 2 nodes.
    __shared__ float Wf[128 * 64];   // 32 KB
    __shared__ float xf[8 * 128];    // 4 KB
    int tid = threadIdx.x;
    // vectorized staging
    const float4* W4 = reinterpret_cast<const float4*>(W1);
    float4* Wf4 = reinterpret_cast<float4*>(Wf);
    for (int i = tid; i < 128 * 64 / 4; i += 256) Wf4[i] = W4[i];
    int node0 = blockIdx.x * 8;
    for (int i = tid; i < 8 * 128; i += 256) {
        int n = node0 + (i >> 7);
        xf[i] = (n < n_nodes) ? x[(size_t)n * 128 + (i & 127)] : 0.f;
    }
    __syncthreads();
    int w = tid >> 6, f = tid & 63;
    int nl0 = w * 2, nl1 = nl0 + 1;
    float acc0 = 0.f, acc1 = 0.f;
#pragma unroll 8
    for (int k = 0; k < 128; ++k) {
        float wv = Wf[k * 64 + f];           // 64 consecutive lanes -> 2 lanes/bank (free)
        acc0 += xf[nl0 * 128 + k] * wv;      // broadcast
        acc1 += xf[nl1 * 128 + k] * wv;      // broadcast
    }
    int n0 = node0 + nl0, n1 = node0 + nl1;
    if (n0 < n_nodes) h1[(size_t)n0 * 64 + f] = acc0;
    if (n1 < n_nodes) h1[(size_t)n1 * 64 + f] = acc1;
}

__global__ void scatter1_kernel(const float* __restrict__ h1,
                                const int* __restrict__ ei,
                                const float* __restrict__ ew,
                                float* __restrict__ agg, int n_edges) {
    int t = blockIdx.x * blockDim.x + threadIdx.x;
    int e = t >> 4;                 // 16 threads per edge, 4 feats each
    if (e >= n_edges) return;
    int f4 = (t & 15) * 4;
    int s = ei[e];
    int d = ei[n_edges + e];
    float we = ew[e];
    const float4 hv = *reinterpret_cast<const float4*>(h1 + (size_t)s * 64 + f4);
    float* out = agg + (size_t)d * 64 + f4;
    atomicAdd(out + 0, hv.x * we);
    atomicAdd(out + 1, hv.y * we);
    atomicAdd(out + 2, hv.z * we);
    atomicAdd(out + 3, hv.w * we);
}

__global__ void gemm2_kernel(const float* __restrict__ agg1,
                             const float* __restrict__ W2,
                             float* __restrict__ h2, int n_nodes) {
    // 16 nodes per block; thread = (node_local, feat) = (tid/16, tid%16). relu fused on load.
    __shared__ float Wf[64 * 16];    // 4 KB
    __shared__ float xf[16 * 65];    // pad 64->65: breaks conflicts across node groups
    int tid = threadIdx.x;
    for (int i = tid; i < 64 * 16; i += 256) Wf[i] = W2[i];
    int node0 = blockIdx.x * 16;
    for (int i = tid; i < 16 * 64; i += 256) {
        int nl = i >> 6, k = i & 63;
        int n = node0 + nl;
        float v = (n < n_nodes) ? agg1[(size_t)n * 64 + k] : 0.f;
        xf[nl * 65 + k] = fmaxf(v, 0.f);
    }
    __syncthreads();
    int nl = tid >> 4, f = tid & 15;
    float acc = 0.f;
#pragma unroll 8
    for (int k = 0; k < 64; ++k) acc += xf[nl * 65 + k] * Wf[k * 16 + f];
    int n = node0 + nl;
    if (n < n_nodes) h2[(size_t)n * 16 + f] = acc;
}

__global__ void scatter2_kernel(const float* __restrict__ h2,
                                const int* __restrict__ ei,
                                const float* __restrict__ ew,
                                float* __restrict__ out_agg, int n_edges) {
    int t = blockIdx.x * blockDim.x + threadIdx.x;
    int e = t >> 2;                 // 4 threads per edge, 4 feats each
    if (e >= n_edges) return;
    int f4 = (t & 3) * 4;
    int s = ei[e];
    int d = ei[n_edges + e];
    float we = ew[e];
    const float4 hv = *reinterpret_cast<const float4*>(h2 + (size_t)s * 16 + f4);
    float* out = out_agg + (size_t)d * 16 + f4;
    atomicAdd(out + 0, hv.x * we);
    atomicAdd(out + 1, hv.y * we);
    atomicAdd(out + 2, hv.z * we);
    atomicAdd(out + 3, hv.w * we);
}

extern "C" void kernel_launch(void* const* d_in, const int* in_sizes, int n_in,
                              void* d_out, int out_size, void* d_ws, size_t ws_size,
                              hipStream_t stream) {
    const float* x   = (const float*)d_in[0];
    const int*   ei1 = (const int*)d_in[1];
    const int*   ei2 = (const int*)d_in[2];
    const float* ew1 = (const float*)d_in[3];
    const float* ew2 = (const float*)d_in[4];
    const float* W1  = (const float*)d_in[5];
    const float* W2  = (const float*)d_in[6];

    const int n_nodes = in_sizes[0] / 128;   // 100000
    const int n_edges = in_sizes[1] / 2;     // 1600000

    float* h1   = (float*)d_ws;                      // N*64
    float* agg1 = h1 + (size_t)n_nodes * 64;         // N*64
    float* h2   = agg1 + (size_t)n_nodes * 64;       // N*16
    float* out  = (float*)d_out;                     // N*16

    // zero accumulators (ws and out are poisoned 0xAA before every call)
    hipMemsetAsync(agg1, 0, (size_t)n_nodes * 64 * sizeof(float), stream);
    hipMemsetAsync(out, 0, (size_t)out_size * sizeof(float), stream);

    gemm1_kernel<<<(n_nodes + 7) / 8, 256, 0, stream>>>(x, W1, h1, n_nodes);

    {
        long long threads = (long long)n_edges * 16;
        scatter1_kernel<<<(unsigned)((threads + 255) / 256), 256, 0, stream>>>(h1, ei1, ew1, agg1, n_edges);
    }

    gemm2_kernel<<<(n_nodes + 15) / 16, 256, 0, stream>>>(agg1, W2, h2, n_nodes);

    {
        long long threads = (long long)n_edges * 4;
        scatter2_kernel<<<(unsigned)((threads + 255) / 256), 256, 0, stream>>>(h2, ei2, ew2, out, n_edges);
    }
}

// Round 3
// 721.266 us; speedup vs baseline: 2.6080x; 2.6080x over previous
//
#include <hip/hip_runtime.h>
#include <hip/hip_bf16.h>

// GCN 2-layer, fp32 I/O, CSR-gather aggregation (no fp32 atomics):
//   h   = relu(segsum_dst((x@W1)[src1] * w1))      128 -> 64
//   out = segsum_dst((h@W2)[src2] * w2)            64 -> 16
// N=100000, E=1600000.

// ---------------- dense layers ----------------

__global__ void gemm1_kernel(const float* __restrict__ x,
                             const float* __restrict__ W1,
                             float* __restrict__ h1, int n_nodes) {
    __shared__ float Wf[128 * 64];   // 32 KB
    __shared__ float xf[8 * 128];    // 4 KB
    int tid = threadIdx.x;
    const float4* W4 = reinterpret_cast<const float4*>(W1);
    float4* Wf4 = reinterpret_cast<float4*>(Wf);
    for (int i = tid; i < 128 * 64 / 4; i += 256) Wf4[i] = W4[i];
    int node0 = blockIdx.x * 8;
    for (int i = tid; i < 8 * 128; i += 256) {
        int n = node0 + (i >> 7);
        xf[i] = (n < n_nodes) ? x[(size_t)n * 128 + (i & 127)] : 0.f;
    }
    __syncthreads();
    int w = tid >> 6, f = tid & 63;
    int nl0 = w * 2, nl1 = nl0 + 1;
    float acc0 = 0.f, acc1 = 0.f;
#pragma unroll 8
    for (int k = 0; k < 128; ++k) {
        float wv = Wf[k * 64 + f];
        acc0 += xf[nl0 * 128 + k] * wv;
        acc1 += xf[nl1 * 128 + k] * wv;
    }
    int n0 = node0 + nl0, n1 = node0 + nl1;
    if (n0 < n_nodes) h1[(size_t)n0 * 64 + f] = acc0;
    if (n1 < n_nodes) h1[(size_t)n1 * 64 + f] = acc1;
}

__global__ void gemm2_kernel(const float* __restrict__ agg1,
                             const float* __restrict__ W2,
                             float* __restrict__ h2, int n_nodes) {
    __shared__ float Wf[64 * 16];
    __shared__ float xf[16 * 65];
    int tid = threadIdx.x;
    for (int i = tid; i < 64 * 16; i += 256) Wf[i] = W2[i];
    int node0 = blockIdx.x * 16;
    for (int i = tid; i < 16 * 64; i += 256) {
        int nl = i >> 6, k = i & 63;
        int n = node0 + nl;
        xf[nl * 65 + k] = (n < n_nodes) ? agg1[(size_t)n * 64 + k] : 0.f;  // relu already applied
    }
    __syncthreads();
    int nl = tid >> 4, f = tid & 15;
    float acc = 0.f;
#pragma unroll 8
    for (int k = 0; k < 64; ++k) acc += xf[nl * 65 + k] * Wf[k * 16 + f];
    int n = node0 + nl;
    if (n < n_nodes) h2[(size_t)n * 16 + f] = acc;
}

// ---------------- CSR build ----------------

__global__ void hist_kernel(const int* __restrict__ ei, int* __restrict__ deg, int n_edges) {
    int e = blockIdx.x * 256 + threadIdx.x;
    if (e < n_edges) atomicAdd(&deg[ei[n_edges + e]], 1);
}

__global__ void scan_local(const int* __restrict__ deg, int* __restrict__ rowptr,
                           int* __restrict__ blocksums, int n) {
    __shared__ int tmp[256];
    int i = blockIdx.x * 256 + threadIdx.x;
    int v = (i < n) ? deg[i] : 0;
    tmp[threadIdx.x] = v;
    __syncthreads();
    for (int off = 1; off < 256; off <<= 1) {
        int t = (threadIdx.x >= off) ? tmp[threadIdx.x - off] : 0;
        __syncthreads();
        tmp[threadIdx.x] += t;
        __syncthreads();
    }
    if (i < n) rowptr[i] = tmp[threadIdx.x] - v;   // exclusive
    if (threadIdx.x == 255) blocksums[blockIdx.x] = tmp[255];
}

__global__ void scan_top(int* __restrict__ blocksums, int nb) {
    __shared__ int tmp[512];
    int v = (threadIdx.x < nb) ? blocksums[threadIdx.x] : 0;
    tmp[threadIdx.x] = v;
    __syncthreads();
    for (int off = 1; off < 512; off <<= 1) {
        int t = (threadIdx.x >= off) ? tmp[threadIdx.x - off] : 0;
        __syncthreads();
        tmp[threadIdx.x] += t;
        __syncthreads();
    }
    if (threadIdx.x < nb) blocksums[threadIdx.x] = tmp[threadIdx.x] - v;  // exclusive
}

__global__ void add_offsets(int* __restrict__ rowptr, const int* __restrict__ blocksums,
                            int n, int n_edges) {
    int i = blockIdx.x * 256 + threadIdx.x;
    if (i < n) rowptr[i] += blocksums[blockIdx.x];
    if (i == 0) rowptr[n] = n_edges;
}

__global__ void fill_csr(const int* __restrict__ ei, const float* __restrict__ ew,
                         int* __restrict__ cursor, int2* __restrict__ csr, int n_edges) {
    int e = blockIdx.x * 256 + threadIdx.x;
    if (e >= n_edges) return;
    int s = ei[e];
    int d = ei[n_edges + e];
    int pos = atomicAdd(&cursor[d], 1);
    csr[pos] = make_int2(s, __float_as_int(ew[e]));
}

// ---------------- gather-side aggregation ----------------

// one wave per dst node, lane = feature (64 feats); relu fused into the store
__global__ void gather1_kernel(const float* __restrict__ h1,
                               const int* __restrict__ rowptr,
                               const int2* __restrict__ csr,
                               float* __restrict__ agg, int n_nodes) {
    int n = blockIdx.x * 4 + (threadIdx.x >> 6);
    if (n >= n_nodes) return;
    int f = threadIdx.x & 63;
    int i = rowptr[n], end = rowptr[n + 1];
    float acc = 0.f;
    for (; i + 1 < end; i += 2) {                // 2-wide: two h1 loads in flight
        int2 e0 = csr[i];
        int2 e1 = csr[i + 1];
        acc += h1[(size_t)e0.x * 64 + f] * __int_as_float(e0.y);
        acc += h1[(size_t)e1.x * 64 + f] * __int_as_float(e1.y);
    }
    if (i < end) {
        int2 e0 = csr[i];
        acc += h1[(size_t)e0.x * 64 + f] * __int_as_float(e0.y);
    }
    agg[(size_t)n * 64 + f] = fmaxf(acc, 0.f);   // fused relu
}

// quarter-wave per dst node (16 feats)
__global__ void gather2_kernel(const float* __restrict__ h2,
                               const int* __restrict__ rowptr,
                               const int2* __restrict__ csr,
                               float* __restrict__ out, int n_nodes) {
    int n = blockIdx.x * 16 + (threadIdx.x >> 4);
    if (n >= n_nodes) return;
    int f = threadIdx.x & 15;
    int i = rowptr[n], end = rowptr[n + 1];
    float acc = 0.f;
    for (; i + 1 < end; i += 2) {
        int2 e0 = csr[i];
        int2 e1 = csr[i + 1];
        acc += h2[(size_t)e0.x * 16 + f] * __int_as_float(e0.y);
        acc += h2[(size_t)e1.x * 16 + f] * __int_as_float(e1.y);
    }
    if (i < end) {
        int2 e0 = csr[i];
        acc += h2[(size_t)e0.x * 16 + f] * __int_as_float(e0.y);
    }
    out[(size_t)n * 16 + f] = acc;
}

// ---------------- launch ----------------

static void build_csr(const int* ei, const float* ew, int* rowptr, int2* csr,
                      int* deg, int* cursor, int* blocksums,
                      int n_nodes, int n_edges, hipStream_t stream) {
    int nb_nodes = (n_nodes + 255) / 256;       // 391
    int nb_edges = (n_edges + 255) / 256;       // 6250
    hipMemsetAsync(deg, 0, (size_t)n_nodes * sizeof(int), stream);
    hist_kernel<<<nb_edges, 256, 0, stream>>>(ei, deg, n_edges);
    scan_local<<<nb_nodes, 256, 0, stream>>>(deg, rowptr, blocksums, n_nodes);
    scan_top<<<1, 512, 0, stream>>>(blocksums, nb_nodes);
    add_offsets<<<nb_nodes, 256, 0, stream>>>(rowptr, blocksums, n_nodes, n_edges);
    hipMemcpyAsync(cursor, rowptr, (size_t)n_nodes * sizeof(int),
                   hipMemcpyDeviceToDevice, stream);
    fill_csr<<<nb_edges, 256, 0, stream>>>(ei, ew, cursor, csr, n_edges);
}

extern "C" void kernel_launch(void* const* d_in, const int* in_sizes, int n_in,
                              void* d_out, int out_size, void* d_ws, size_t ws_size,
                              hipStream_t stream) {
    const float* x   = (const float*)d_in[0];
    const int*   ei1 = (const int*)d_in[1];
    const int*   ei2 = (const int*)d_in[2];
    const float* ew1 = (const float*)d_in[3];
    const float* ew2 = (const float*)d_in[4];
    const float* W1  = (const float*)d_in[5];
    const float* W2  = (const float*)d_in[6];

    const int n_nodes = in_sizes[0] / 128;   // 100000
    const int n_edges = in_sizes[1] / 2;     // 1600000

    // ws layout (4-byte units)
    float* h1       = (float*)d_ws;                         // N*64
    float* agg1     = h1 + (size_t)n_nodes * 64;            // N*64
    float* h2       = agg1 + (size_t)n_nodes * 64;          // N*16
    int*   rowptr1  = (int*)(h2 + (size_t)n_nodes * 16);    // N+1
    int*   rowptr2  = rowptr1 + (n_nodes + 1);              // N+1
    int2*  csr1     = (int2*)(rowptr2 + (n_nodes + 1));     // E int2
    int2*  csr2     = csr1 + n_edges;                       // E int2
    int*   deg      = (int*)(csr2 + n_edges);               // N
    int*   cursor   = deg + n_nodes;                        // N
    int*   blocksums= cursor + n_nodes;                     // 512

    float* out = (float*)d_out;

    // layer 1
    gemm1_kernel<<<(n_nodes + 7) / 8, 256, 0, stream>>>(x, W1, h1, n_nodes);
    build_csr(ei1, ew1, rowptr1, csr1, deg, cursor, blocksums, n_nodes, n_edges, stream);
    gather1_kernel<<<(n_nodes + 3) / 4, 256, 0, stream>>>(h1, rowptr1, csr1, agg1, n_nodes);

    // layer 2
    gemm2_kernel<<<(n_nodes + 15) / 16, 256, 0, stream>>>(agg1, W2, h2, n_nodes);
    build_csr(ei2, ew2, rowptr2, csr2, deg, cursor, blocksums, n_nodes, n_edges, stream);
    gather2_kernel<<<(n_nodes + 15) / 16, 256, 0, stream>>>(h2, rowptr2, csr2, out, n_nodes);
}